// Round 1
// baseline (211.384 us; speedup 1.0000x reference)
//
#include <hip/hip_runtime.h>

#define SEQ 2048
#define EMB 128
#define QT 64
#define KT 64
#define NTHREADS 256
#define EP 136   // K/Q LDS row stride in bf16 elems (128 + 8 pad, keeps 16B align)
#define VP 72    // Vt/Ps LDS row stride (64 + 8 pad)

typedef __attribute__((ext_vector_type(8))) short short8;
typedef __attribute__((ext_vector_type(4))) float floatx4;
typedef __attribute__((ext_vector_type(4))) unsigned short ushort4_t;

// fp32 -> bf16 round-to-nearest-even (inputs are finite randn; no NaN path needed)
__device__ __forceinline__ unsigned short f2bf(float x) {
  union { float f; unsigned u; } c; c.f = x;
  return (unsigned short)((c.u + 0x7fffu + ((c.u >> 16) & 1u)) >> 16);
}

__global__ __launch_bounds__(NTHREADS, 2)
void fattn_kernel(const float* __restrict__ Qp, const float* __restrict__ Kp,
                  const float* __restrict__ Vp, float* __restrict__ Op) {
  // 62464 B total LDS -> 2 blocks/CU
  __shared__ __align__(16) unsigned short Qs[QT][EP];
  __shared__ __align__(16) unsigned short Ks[KT][EP];
  __shared__ __align__(16) unsigned short Vt[EMB][VP];  // V transposed: [e][k]
  __shared__ __align__(16) unsigned short Ps[QT][VP];   // P tile for C->A layout

  const int tid  = threadIdx.x;
  const int lane = tid & 63;
  const int w    = tid >> 6;         // wave 0..3, owns q rows [w*16, w*16+16)
  const int n16  = lane & 15;
  const int quad = lane >> 4;
  const int wq0  = w * 16;
  const int b    = blockIdx.y;
  const int q0   = blockIdx.x * QT;
  const size_t base = (size_t)b * SEQ * EMB;
  const float* Qg = Qp + base + (size_t)q0 * EMB;
  const float* Kg = Kp + base;
  const float* Vg = Vp + base;

  // ---- stage Q tile (64x128 fp32 -> bf16), coalesced float4 ----
#pragma unroll
  for (int i = 0; i < 8; ++i) {
    int id = tid + i * NTHREADS;
    int r = id >> 5, c = (id & 31) << 2;
    float4 v = *(const float4*)(Qg + (size_t)r * EMB + c);
    *(ushort4_t*)&Qs[r][c] = (ushort4_t){f2bf(v.x), f2bf(v.y), f2bf(v.z), f2bf(v.w)};
  }

  float m_i[4], l_i[4];
  floatx4 o[8];
#pragma unroll
  for (int i = 0; i < 4; ++i) { m_i[i] = -3.0e38f; l_i[i] = 0.f; }
#pragma unroll
  for (int t = 0; t < 8; ++t) o[t] = (floatx4){0.f, 0.f, 0.f, 0.f};

  const float L2E = 1.4426950408889634f;
  const float C1  = 0.08838834764831845f * L2E;  // scale * log2(e)

  for (int kt = 0; kt < SEQ; kt += KT) {
    __syncthreads();  // previous iteration's LDS reads done before restaging

    // ---- stage K tile (row-major bf16) ----
#pragma unroll
    for (int i = 0; i < 8; ++i) {
      int id = tid + i * NTHREADS;
      int r = id >> 5, c = (id & 31) << 2;
      float4 v = *(const float4*)(Kg + (size_t)(kt + r) * EMB + c);
      *(ushort4_t*)&Ks[r][c] = (ushort4_t){f2bf(v.x), f2bf(v.y), f2bf(v.z), f2bf(v.w)};
    }
    // ---- stage V transposed via register 4x4 transpose ----
    {
      const int k  = (tid & 15) << 2;   // k col group
      const int e0 = (tid >> 4) << 2;   // e row group
#pragma unroll
      for (int eo = 0; eo < 2; ++eo) {
        int e = e0 + eo * 64;
        const float* vb = Vg + (size_t)(kt + k) * EMB + e;
        float4 r0 = *(const float4*)(vb);
        float4 r1 = *(const float4*)(vb + EMB);
        float4 r2 = *(const float4*)(vb + 2 * EMB);
        float4 r3 = *(const float4*)(vb + 3 * EMB);
        *(ushort4_t*)&Vt[e + 0][k] = (ushort4_t){f2bf(r0.x), f2bf(r1.x), f2bf(r2.x), f2bf(r3.x)};
        *(ushort4_t*)&Vt[e + 1][k] = (ushort4_t){f2bf(r0.y), f2bf(r1.y), f2bf(r2.y), f2bf(r3.y)};
        *(ushort4_t*)&Vt[e + 2][k] = (ushort4_t){f2bf(r0.z), f2bf(r1.z), f2bf(r2.z), f2bf(r3.z)};
        *(ushort4_t*)&Vt[e + 3][k] = (ushort4_t){f2bf(r0.w), f2bf(r1.w), f2bf(r2.w), f2bf(r3.w)};
      }
    }
    __syncthreads();

    // ---- S = Q K^T : wave computes 16q x 64k, K-dim = EMB in 4 steps ----
    floatx4 sfr[4];
#pragma unroll
    for (int f = 0; f < 4; ++f) sfr[f] = (floatx4){0.f, 0.f, 0.f, 0.f};
#pragma unroll
    for (int e0 = 0; e0 < EMB; e0 += 32) {
      short8 a = *(const short8*)&Qs[wq0 + n16][e0 + quad * 8];  // A[m=n16][k=quad*8+j]
#pragma unroll
      for (int f = 0; f < 4; ++f) {
        short8 bb = *(const short8*)&Ks[f * 16 + n16][e0 + quad * 8];  // B[k][n=n16]
        sfr[f] = __builtin_amdgcn_mfma_f32_16x16x32_bf16(a, bb, sfr[f], 0, 0, 0);
      }
    }

    // ---- online softmax; C layout: col=n16, row=quad*4+i ----
    float mnew[4], alpha[4];
#pragma unroll
    for (int i = 0; i < 4; ++i) {
      float t0 = fmaxf(fmaxf(sfr[0][i], sfr[1][i]), fmaxf(sfr[2][i], sfr[3][i]));
      t0 = fmaxf(t0, __shfl_xor(t0, 1));
      t0 = fmaxf(t0, __shfl_xor(t0, 2));
      t0 = fmaxf(t0, __shfl_xor(t0, 4));
      t0 = fmaxf(t0, __shfl_xor(t0, 8));
      mnew[i]  = fmaxf(m_i[i], t0 * 0.08838834764831845f);
      alpha[i] = __builtin_amdgcn_exp2f((m_i[i] - mnew[i]) * L2E);
      m_i[i] = mnew[i];
    }
    float rs[4] = {0.f, 0.f, 0.f, 0.f};
#pragma unroll
    for (int f = 0; f < 4; ++f) {
#pragma unroll
      for (int i = 0; i < 4; ++i) {
        float p = __builtin_amdgcn_exp2f(fmaf(sfr[f][i], C1, -mnew[i] * L2E));
        rs[i] += p;
        Ps[wq0 + quad * 4 + i][f * 16 + n16] = f2bf(p);
      }
    }
#pragma unroll
    for (int i = 0; i < 4; ++i) {
      float r = rs[i];
      r += __shfl_xor(r, 1);
      r += __shfl_xor(r, 2);
      r += __shfl_xor(r, 4);
      r += __shfl_xor(r, 8);
      l_i[i] = l_i[i] * alpha[i] + r;
    }
#pragma unroll
    for (int t = 0; t < 8; ++t)
#pragma unroll
      for (int i = 0; i < 4; ++i) o[t][i] *= alpha[i];

    __syncthreads();  // order Ps writes vs A-frag reads (compiler + HW safe)

    // ---- O += P V : A from Ps (wave-private rows), B from Vt ----
#pragma unroll
    for (int k0 = 0; k0 < KT; k0 += 32) {
      short8 a = *(const short8*)&Ps[wq0 + n16][k0 + quad * 8];
#pragma unroll
      for (int t = 0; t < 8; ++t) {
        short8 bb = *(const short8*)&Vt[t * 16 + n16][k0 + quad * 8];
        o[t] = __builtin_amdgcn_mfma_f32_16x16x32_bf16(a, bb, o[t], 0, 0, 0);
      }
    }
  }

  // ---- epilogue: O / l, fp32 store ----
  float* Og = Op + base + (size_t)q0 * EMB;
#pragma unroll
  for (int i = 0; i < 4; ++i) {
    float inv = 1.0f / l_i[i];
    int row = wq0 + quad * 4 + i;
#pragma unroll
    for (int t = 0; t < 8; ++t)
      Og[(size_t)row * EMB + t * 16 + n16] = o[t][i] * inv;
  }
}

extern "C" void kernel_launch(void* const* d_in, const int* in_sizes, int n_in,
                              void* d_out, int out_size, void* d_ws, size_t ws_size,
                              hipStream_t stream) {
  const float* Q = (const float*)d_in[0];
  const float* K = (const float*)d_in[1];
  const float* V = (const float*)d_in[2];
  float* O = (float*)d_out;
  const int B = in_sizes[0] / (SEQ * EMB);
  dim3 grid(SEQ / QT, B);
  fattn_kernel<<<grid, NTHREADS, 0, stream>>>(Q, K, V, O);
}

// Round 2
// 169.313 us; speedup vs baseline: 1.2485x; 1.2485x over previous
//
#include <hip/hip_runtime.h>

#define SEQ 2048
#define EMB 128
#define KT 64
#define QT 64
#define NT 256
#define NITER (SEQ / KT)

typedef __attribute__((ext_vector_type(8))) short short8;
typedef __attribute__((ext_vector_type(4))) float floatx4;
typedef unsigned short ushort_t;
typedef __attribute__((ext_vector_type(4))) unsigned short ushort4_t;

__device__ __forceinline__ unsigned short f2bf(float x) {
  union { float f; unsigned u; } c; c.f = x;
  return (unsigned short)((c.u + 0x7fffu + ((c.u >> 16) & 1u)) >> 16);
}
__device__ __forceinline__ unsigned packbf(float a, float b) {
  return (unsigned)f2bf(a) | ((unsigned)f2bf(b) << 16);
}

// ---- pre-pass 1: fp32 -> bf16 elementwise ----
__global__ void cvt_bf16_kernel(const float* __restrict__ in, unsigned short* __restrict__ out, int n4) {
  int i = blockIdx.x * blockDim.x + threadIdx.x;
  if (i >= n4) return;
  float4 v = ((const float4*)in)[i];
  ((ushort4_t*)out)[i] = (ushort4_t){f2bf(v.x), f2bf(v.y), f2bf(v.z), f2bf(v.w)};
}

// ---- pre-pass 2: V[b][s][e] fp32 -> Vt[b][e][s] bf16 (64x64 LDS tiles) ----
__global__ void transpose_v_kernel(const float* __restrict__ V, unsigned short* __restrict__ Vt) {
  __shared__ unsigned short t[64][72];
  const int s0 = blockIdx.x * 64, e0 = blockIdx.y * 64, b = blockIdx.z;
  const float* src = V + (size_t)b * SEQ * EMB;
  unsigned short* dst = Vt + (size_t)b * EMB * SEQ;
  const int tid = threadIdx.x;
  const int c4 = (tid & 15) * 4, r = tid >> 4;
#pragma unroll
  for (int j = 0; j < 4; ++j) {
    int sr = r + j * 16;
    float4 v = *(const float4*)(src + (size_t)(s0 + sr) * EMB + e0 + c4);
    t[c4 + 0][sr] = f2bf(v.x);
    t[c4 + 1][sr] = f2bf(v.y);
    t[c4 + 2][sr] = f2bf(v.z);
    t[c4 + 3][sr] = f2bf(v.w);
  }
  __syncthreads();
#pragma unroll
  for (int j = 0; j < 4; ++j) {
    int er = r + j * 16;
    ushort4_t o = {t[er][c4], t[er][c4 + 1], t[er][c4 + 2], t[er][c4 + 3]};
    *(ushort4_t*)(dst + (size_t)(e0 + er) * SEQ + s0 + c4) = o;
  }
}

// ---- main flash kernel: S^T = K Q^T, O^T = Vt P^T ----
__global__ __launch_bounds__(NT, 2)
void fattn2(const unsigned short* __restrict__ Qb, const unsigned short* __restrict__ Kb,
            const unsigned short* __restrict__ Vtb, float* __restrict__ Op) {
  // 65536 B total -> 2 blocks/CU. Un-padded (global_load_lds), XOR-swizzled:
  // 16B group g of row r lives at slot g ^ (r&7).
  __shared__ __align__(16) unsigned short Ks[2][KT][EMB];   // 32 KB
  __shared__ __align__(16) unsigned short Vs[2][EMB][KT];   // 32 KB

  const int tid  = threadIdx.x;
  const int lane = tid & 63;
  const int w    = tid >> 6;
  const int n16  = lane & 15, quad = lane >> 4;
  const int b    = blockIdx.y, q0 = blockIdx.x * QT;
  const size_t bo = (size_t)b * SEQ * EMB;

  auto* ks3 = (__attribute__((address_space(3))) unsigned short*)&Ks[0][0][0];
  auto* vs3 = (__attribute__((address_space(3))) unsigned short*)&Vs[0][0][0];
  const unsigned short* ksl = &Ks[0][0][0];
  const unsigned short* vsl = &Vs[0][0][0];

  // staging source pointers (per-lane, XOR-swizzled within rows)
  const int krw = tid >> 4, kgs = tid & 15;
  const int vrw = tid >> 3, vgs = tid & 7;
  const unsigned short* pK = Kb + bo + (size_t)krw * EMB + (size_t)((kgs ^ (krw & 7)) * 8);
  const unsigned short* pV = Vtb + bo + (size_t)vrw * SEQ + (size_t)((vgs ^ (vrw & 7)) * 8);

  // Q fragments: lane's own q-row (q = q0 + w*16 + n16), 4 chunks of 8 bf16
  short8 qf[4];
  {
    const unsigned short* qr = Qb + bo + (size_t)(q0 + w * 16 + n16) * EMB + quad * 8;
#pragma unroll
    for (int e = 0; e < 4; ++e) qf[e] = *(const short8*)(qr + e * 32);
  }

  // swizzled column offsets for compute-phase reads (ushort units)
  int koff[4], voff[2];
#pragma unroll
  for (int e = 0; e < 4; ++e) koff[e] = ((e * 4 + quad) ^ (n16 & 7)) * 8;
#pragma unroll
  for (int k = 0; k < 2; ++k) voff[k] = ((k * 4 + quad) ^ (n16 & 7)) * 8;

  floatx4 o[8];
#pragma unroll
  for (int t = 0; t < 8; ++t) o[t] = (floatx4){0.f, 0.f, 0.f, 0.f};
  float m_i = -3.0e38f, l_i = 0.f;

  const float SCALE = 0.08838834764831845f;
  const float L2E = 1.4426950408889634f;
  const float C1 = SCALE * L2E;

  // issue async loads for one K/V tile into buffer `buf`, advance pointers
  auto issue = [&](int buf) {
    auto* kb = ks3 + buf * (KT * EMB) + w * 512;
    auto* vb = vs3 + buf * (EMB * KT) + w * 512;
    const unsigned short* gv = pV;
#pragma unroll
    for (int j = 0; j < 4; ++j) {
      __builtin_amdgcn_global_load_lds((const __attribute__((address_space(1))) void*)pK,
                                       (__attribute__((address_space(3))) void*)(kb + j * 2048), 16, 0, 0);
      pK += 2048;  // 16 rows; 4 calls advance exactly one tile (KT*EMB)
      __builtin_amdgcn_global_load_lds((const __attribute__((address_space(1))) void*)gv,
                                       (__attribute__((address_space(3))) void*)(vb + j * 2048), 16, 0, 0);
      gv += 32 * SEQ;  // 32 rows per round
    }
    pV += KT;  // next k-tile
  };

  issue(0);

  const int L1 = n16 + ((quad & 1) ? 32 : 0);  // P-transpose source lanes
  const int L2v = L1 + 16;
  const bool hi = quad >= 2;

  for (int it = 0; it < NITER; ++it) {
    const int cur = it & 1;
    __syncthreads();  // drains vmcnt -> buf[cur] ready; prior reads of buf[cur^1] done
    if (it + 1 < NITER) issue(cur ^ 1);

    // ---- S^T = K Q^T : A = K rows (m=k), B = Q regs (n=q) ----
    floatx4 s[4];
#pragma unroll
    for (int f = 0; f < 4; ++f) s[f] = (floatx4){0.f, 0.f, 0.f, 0.f};
    const unsigned short* kbase = ksl + cur * (KT * EMB);
#pragma unroll
    for (int e = 0; e < 4; ++e) {
#pragma unroll
      for (int f = 0; f < 4; ++f) {
        short8 ak = *(const short8*)(kbase + (f * 16 + n16) * EMB + koff[e]);
        s[f] = __builtin_amdgcn_mfma_f32_16x16x32_bf16(ak, qf[e], s[f], 0, 0, 0);
      }
    }

    // ---- online softmax (lane owns one q; 16 k-values in-lane, 4 quads cross-lane) ----
    float mx = s[0][0];
#pragma unroll
    for (int f = 0; f < 4; ++f)
#pragma unroll
      for (int i = 0; i < 4; ++i) mx = fmaxf(mx, s[f][i]);
    mx = fmaxf(mx, __shfl_xor(mx, 16));
    mx = fmaxf(mx, __shfl_xor(mx, 32));
    float mnew = fmaxf(m_i, mx * SCALE);
    float alpha = __builtin_amdgcn_exp2f((m_i - mnew) * L2E);
    m_i = mnew;
    const float c2 = mnew * L2E;
    float p[4][4];
    float rs = 0.f;
#pragma unroll
    for (int f = 0; f < 4; ++f)
#pragma unroll
      for (int i = 0; i < 4; ++i) {
        p[f][i] = __builtin_amdgcn_exp2f(fmaf(s[f][i], C1, -c2));
        rs += p[f][i];
      }
    rs += __shfl_xor(rs, 16);
    rs += __shfl_xor(rs, 32);
    l_i = l_i * alpha + rs;

    unsigned pf0[4], pf1[4];
#pragma unroll
    for (int f = 0; f < 4; ++f) { pf0[f] = packbf(p[f][0], p[f][1]); pf1[f] = packbf(p[f][2], p[f][3]); }
#pragma unroll
    for (int t = 0; t < 8; ++t)
#pragma unroll
      for (int i = 0; i < 4; ++i) o[t][i] *= alpha;

    // ---- O^T += Vt P^T : A = Vt rows (m=e), B = P^T built via shuffles ----
    const unsigned short* vbase = vsl + cur * (EMB * KT);
#pragma unroll
    for (int k0 = 0; k0 < 2; ++k0) {
      const int f0 = k0 * 2, f1 = f0 + 1;
      unsigned a0 = __shfl(pf0[f0], L1), a1 = __shfl(pf1[f0], L1);
      unsigned a2 = __shfl(pf0[f0], L2v), a3 = __shfl(pf1[f0], L2v);
      unsigned b0 = __shfl(pf0[f1], L1), b1 = __shfl(pf1[f1], L1);
      unsigned b2 = __shfl(pf0[f1], L2v), b3 = __shfl(pf1[f1], L2v);
      union { unsigned u[4]; short8 v; } bf;
      bf.u[0] = hi ? b0 : a0;
      bf.u[1] = hi ? b1 : a1;
      bf.u[2] = hi ? b2 : a2;
      bf.u[3] = hi ? b3 : a3;
#pragma unroll
      for (int t = 0; t < 8; ++t) {
        short8 av = *(const short8*)(vbase + (t * 16 + n16) * KT + voff[k0]);
        o[t] = __builtin_amdgcn_mfma_f32_16x16x32_bf16(av, bf.v, o[t], 0, 0, 0);
      }
    }
  }

  // ---- epilogue: lane's q-row, e = t*16 + quad*4 + i ----
  const float inv = 1.0f / l_i;
  float* orow = Op + bo + (size_t)(q0 + w * 16 + n16) * EMB + quad * 4;
#pragma unroll
  for (int t = 0; t < 8; ++t) {
    float4 st = {o[t][0] * inv, o[t][1] * inv, o[t][2] * inv, o[t][3] * inv};
    *(float4*)(orow + t * 16) = st;
  }
}

extern "C" void kernel_launch(void* const* d_in, const int* in_sizes, int n_in,
                              void* d_out, int out_size, void* d_ws, size_t ws_size,
                              hipStream_t stream) {
  const float* Q = (const float*)d_in[0];
  const float* K = (const float*)d_in[1];
  const float* V = (const float*)d_in[2];
  float* O = (float*)d_out;
  const int B = in_sizes[0] / (SEQ * EMB);
  const size_t tsz = (size_t)B * SEQ * EMB;

  unsigned short* Qb = (unsigned short*)d_ws;
  unsigned short* Kb = Qb + tsz;
  unsigned short* Vtb = Kb + tsz;

  const int n4 = (int)(tsz / 4);
  cvt_bf16_kernel<<<n4 / 256, 256, 0, stream>>>(Q, Qb, n4);
  cvt_bf16_kernel<<<n4 / 256, 256, 0, stream>>>(K, Kb, n4);
  transpose_v_kernel<<<dim3(SEQ / 64, EMB / 64, B), 256, 0, stream>>>(V, Vtb);
  fattn2<<<dim3(SEQ / QT, B), NT, 0, stream>>>(Qb, Kb, Vtb, O);
}